// Round 1
// baseline (4177.760 us; speedup 1.0000x reference)
//
#include <hip/hip_runtime.h>
#include <math.h>

#define N_NODES 50000
#define N_EDGES 800000
#define DIM 128
#define ET 32  // edges (or nodes) per block

__device__ __forceinline__ float silu_f(float v) { return v / (1.f + __expf(-v)); }

// ---------------- BatchNorm ----------------
__global__ void bn_stats_kernel(const float* __restrict__ h, float* __restrict__ stats) {
  const int c = threadIdx.x & 127;
  const int rs = threadIdx.x >> 7;
  float s = 0.f, s2 = 0.f;
  for (int row = blockIdx.x * 2 + rs; row < N_NODES; row += gridDim.x * 2) {
    float v = h[(size_t)row * DIM + c];
    s += v;
    s2 += v * v;
  }
  __shared__ float red[256];
  red[threadIdx.x] = s;
  __syncthreads();
  if (threadIdx.x < 128) atomicAdd(&stats[c], red[c] + red[c + 128]);
  __syncthreads();
  red[threadIdx.x] = s2;
  __syncthreads();
  if (threadIdx.x < 128) atomicAdd(&stats[DIM + c], red[c] + red[c + 128]);
}

__global__ void bn_finalize_kernel(float* __restrict__ stats, const float* __restrict__ gamma,
                                   const float* __restrict__ beta) {
  const int c = threadIdx.x;  // 128 threads
  const float inv_n = 1.f / (float)N_NODES;
  float mean = stats[c] * inv_n;
  float var = stats[DIM + c] * inv_n - mean * mean;
  float s = gamma[c] * rsqrtf(var + 1e-5f);
  stats[2 * DIM + c] = s;
  stats[3 * DIM + c] = beta[c] - mean * s;
}

__global__ void bn_apply_kernel(const float* __restrict__ h, const float* __restrict__ stats,
                                float* __restrict__ hn) {
  const int i4 = blockIdx.x * blockDim.x + threadIdx.x;
  if (i4 >= N_NODES * DIM / 4) return;
  const int c4 = i4 & 31;  // float4 column within the 128-wide row
  const float4 v = ((const float4*)h)[i4];
  const float4 a = ((const float4*)(stats + 2 * DIM))[c4];
  const float4 b = ((const float4*)(stats + 3 * DIM))[c4];
  float4 o;
  o.x = v.x * a.x + b.x;
  o.y = v.y * a.y + b.y;
  o.z = v.z * a.z + b.z;
  o.w = v.w * a.w + b.w;
  ((float4*)hn)[i4] = o;
}

// 16-FMA outer product micro-tile
#define FMA16(a, w, A)                                                                   \
  A[0][0] += a.x * w.x; A[0][1] += a.x * w.y; A[0][2] += a.x * w.z; A[0][3] += a.x * w.w; \
  A[1][0] += a.y * w.x; A[1][1] += a.y * w.y; A[1][2] += a.y * w.z; A[1][3] += a.y * w.w; \
  A[2][0] += a.z * w.x; A[2][1] += a.z * w.y; A[2][2] += a.z * w.z; A[2][3] += a.z * w.w; \
  A[3][0] += a.w * w.x; A[3][1] += a.w * w.y; A[3][2] += a.w * w.z; A[3][3] += a.w * w.w;

// ---------------- Edge MLP + gate + scatter ----------------
__launch_bounds__(256, 3)
__global__ void edge_kernel(const float* __restrict__ hn, const float* __restrict__ x,
                            const int* __restrict__ eidx, const float* __restrict__ w1,
                            const float* __restrict__ b1, const float* __restrict__ w2,
                            const float* __restrict__ b2, const float* __restrict__ winf,
                            const float* __restrict__ binf, float* __restrict__ mi) {
  __shared__ float Tt[257 * 32];  // k-major activation tile, XOR-swizzled columns
  __shared__ float Wt[32 * 129];  // transposed weight chunk, padded stride
  __shared__ int esrc[ET];
  __shared__ int edst[ET];
  __shared__ float gate[ET];
  float* red = Wt;  // reuse Wt space for gate reduction

  const int tid = threadIdx.x;
  const int ebase = blockIdx.x * ET;

  if (tid < ET)
    esrc[tid] = eidx[ebase + tid];
  else if (tid < 2 * ET)
    edst[tid - ET] = eidx[N_EDGES + ebase + (tid - ET)];
  __syncthreads();

  // ---- stage Tt[k][e] (k=0..127 src row, 128..255 dst row, 256 dist) ----
  {
    const int el = tid >> 3;   // edge 0..31
    const int part = tid & 7;  // 16 k's per part per half
    const float* hs = hn + (size_t)esrc[el] * DIM + part * 16;
    const float* hd = hn + (size_t)edst[el] * DIM + part * 16;
#pragma unroll
    for (int j = 0; j < 4; ++j) {
      const float4 v = *(const float4*)(hs + j * 4);
      const int k0 = part * 16 + j * 4;
      const int col = el ^ (((k0 >> 4) & 7) << 2);
      Tt[(k0 + 0) * 32 + col] = v.x;
      Tt[(k0 + 1) * 32 + col] = v.y;
      Tt[(k0 + 2) * 32 + col] = v.z;
      Tt[(k0 + 3) * 32 + col] = v.w;
    }
#pragma unroll
    for (int j = 0; j < 4; ++j) {
      const float4 v = *(const float4*)(hd + j * 4);
      const int k0 = 128 + part * 16 + j * 4;
      const int col = el ^ (((k0 >> 4) & 7) << 2);
      Tt[(k0 + 0) * 32 + col] = v.x;
      Tt[(k0 + 1) * 32 + col] = v.y;
      Tt[(k0 + 2) * 32 + col] = v.z;
      Tt[(k0 + 3) * 32 + col] = v.w;
    }
    if (tid < ET) {
      const int s = esrc[tid], d = edst[tid];
      const float dx = x[s * 3 + 0] - x[d * 3 + 0];
      const float dy = x[s * 3 + 1] - x[d * 3 + 1];
      const float dz = x[s * 3 + 2] - x[d * 3 + 2];
      Tt[256 * 32 + tid] = sqrtf(dx * dx + dy * dy + dz * dz);
    }
  }

  const int eq = tid & 7;   // edge quad: edges eq*4..+3
  const int oq = tid >> 3;  // out quad: outs oq*4..+3
  const int eq4 = eq * 4;
  const int oq4 = oq * 4;

  // ---- GEMM1: [32 edges] x W1^T (K = 257) ----
  float acc[4][4] = {};
  for (int kb = 0; kb < 256; kb += 32) {
    __syncthreads();
    for (int i = tid; i < 4096; i += 256) {
      const int kk = i & 31, o = i >> 5;
      Wt[kk * 129 + o] = w1[(size_t)o * 257 + kb + kk];
    }
    __syncthreads();
#pragma unroll
    for (int h2 = 0; h2 < 2; ++h2) {
      const int S = (((kb >> 4) + h2) & 7) << 2;
      const float* tb = &Tt[(kb + h2 * 16) * 32 + (eq4 ^ S)];
      const float* wb = &Wt[(h2 * 16) * 129 + oq4];
#pragma unroll
      for (int kk = 0; kk < 16; ++kk) {
        const float4 a = *(const float4*)(tb + kk * 32);
        const float4 w = *(const float4*)(wb + kk * 129);
        FMA16(a, w, acc)
      }
    }
  }
  // tail k = 256 (dist column of W1)
  __syncthreads();
  if (tid < 128) Wt[tid] = w1[(size_t)tid * 257 + 256];
  __syncthreads();
  {
    const float4 a = *(const float4*)&Tt[256 * 32 + eq4];
    const float4 w = *(const float4*)&Wt[oq4];
    FMA16(a, w, acc)
  }
  __syncthreads();  // everyone done reading Tt before overwrite

  // ---- bias + SiLU, restage as Tt2[o][e] ----
#pragma unroll
  for (int j = 0; j < 4; ++j) {
    const float bb = b1[oq4 + j];
    float4 v;
    v.x = silu_f(acc[0][j] + bb);
    v.y = silu_f(acc[1][j] + bb);
    v.z = silu_f(acc[2][j] + bb);
    v.w = silu_f(acc[3][j] + bb);
    const int o = oq4 + j;
    *(float4*)&Tt[o * 32 + (eq4 ^ (((o >> 2) & 7) << 2))] = v;
  }

  // ---- GEMM2: K = 128 ----
  float acc2[4][4] = {};
  for (int kb = 0; kb < 128; kb += 32) {
    __syncthreads();
    for (int i = tid; i < 4096; i += 256) {
      const int kk = i & 31, o = i >> 5;
      Wt[kk * 129 + o] = w2[(size_t)o * 128 + kb + kk];
    }
    __syncthreads();
#pragma unroll
    for (int q = 0; q < 8; ++q) {
      const int S = q << 2;  // ((kb + q*4) >> 2) & 7 == q for kb % 32 == 0
      const float* tb = &Tt[(kb + q * 4) * 32 + (eq4 ^ S)];
      const float* wb = &Wt[(q * 4) * 129 + oq4];
#pragma unroll
      for (int kk = 0; kk < 4; ++kk) {
        const float4 a = *(const float4*)(tb + kk * 32);
        const float4 w = *(const float4*)(wb + kk * 129);
        FMA16(a, w, acc2)
      }
    }
  }
  __syncthreads();  // done with Wt; red aliases it

  // ---- bias + SiLU -> m2; gate = sigmoid(<m2, winf> + binf) ----
  float m2[4][4];
#pragma unroll
  for (int j = 0; j < 4; ++j) {
    const float bb = b2[oq4 + j];
#pragma unroll
    for (int i = 0; i < 4; ++i) m2[i][j] = silu_f(acc2[i][j] + bb);
  }
  {
    const float g0 = winf[oq4 + 0], g1 = winf[oq4 + 1], g2 = winf[oq4 + 2], g3 = winf[oq4 + 3];
#pragma unroll
    for (int i = 0; i < 4; ++i) {
      red[(eq4 + i) * 33 + oq] = m2[i][0] * g0 + m2[i][1] * g1 + m2[i][2] * g2 + m2[i][3] * g3;
    }
  }
  __syncthreads();
  if (tid < ET) {
    float s = 0.f;
#pragma unroll
    for (int q = 0; q < 32; ++q) s += red[tid * 33 + q];
    gate[tid] = 1.f / (1.f + __expf(-(s + binf[0])));
  }
  __syncthreads();

  // ---- gated atomic scatter into m_i[src] ----
#pragma unroll
  for (int i = 0; i < 4; ++i) {
    const int el = eq4 + i;
    const float g = gate[el];
    float* dp = mi + (size_t)esrc[el] * DIM + oq4;
    atomicAdd(dp + 0, g * m2[i][0]);
    atomicAdd(dp + 1, g * m2[i][1]);
    atomicAdd(dp + 2, g * m2[i][2]);
    atomicAdd(dp + 3, g * m2[i][3]);
  }
}

// ---------------- Node MLP with residual ----------------
__launch_bounds__(256, 3)
__global__ void node_kernel(const float* __restrict__ hn, const float* __restrict__ mi,
                            const float* __restrict__ w1, const float* __restrict__ b1,
                            const float* __restrict__ w2, const float* __restrict__ b2,
                            float* __restrict__ out) {
  __shared__ float Tt[256 * 32];
  __shared__ float Wt[32 * 129];
  const int tid = threadIdx.x;
  const int nbase = blockIdx.x * ET;

  {
    const int el = tid >> 3;
    const int part = tid & 7;
    int node = nbase + el;
    if (node >= N_NODES) node = N_NODES - 1;  // clamp; outputs are guarded
    const float* hs = hn + (size_t)node * DIM + part * 16;
    const float* ms = mi + (size_t)node * DIM + part * 16;
#pragma unroll
    for (int j = 0; j < 4; ++j) {
      const float4 v = *(const float4*)(hs + j * 4);
      const int k0 = part * 16 + j * 4;
      const int col = el ^ (((k0 >> 4) & 7) << 2);
      Tt[(k0 + 0) * 32 + col] = v.x;
      Tt[(k0 + 1) * 32 + col] = v.y;
      Tt[(k0 + 2) * 32 + col] = v.z;
      Tt[(k0 + 3) * 32 + col] = v.w;
    }
#pragma unroll
    for (int j = 0; j < 4; ++j) {
      const float4 v = *(const float4*)(ms + j * 4);
      const int k0 = 128 + part * 16 + j * 4;
      const int col = el ^ (((k0 >> 4) & 7) << 2);
      Tt[(k0 + 0) * 32 + col] = v.x;
      Tt[(k0 + 1) * 32 + col] = v.y;
      Tt[(k0 + 2) * 32 + col] = v.z;
      Tt[(k0 + 3) * 32 + col] = v.w;
    }
  }

  const int eq = tid & 7;
  const int oq = tid >> 3;
  const int eq4 = eq * 4;
  const int oq4 = oq * 4;

  float acc[4][4] = {};
  for (int kb = 0; kb < 256; kb += 32) {
    __syncthreads();
    for (int i = tid; i < 4096; i += 256) {
      const int kk = i & 31, o = i >> 5;
      Wt[kk * 129 + o] = w1[(size_t)o * 256 + kb + kk];
    }
    __syncthreads();
#pragma unroll
    for (int h2 = 0; h2 < 2; ++h2) {
      const int S = (((kb >> 4) + h2) & 7) << 2;
      const float* tb = &Tt[(kb + h2 * 16) * 32 + (eq4 ^ S)];
      const float* wb = &Wt[(h2 * 16) * 129 + oq4];
#pragma unroll
      for (int kk = 0; kk < 16; ++kk) {
        const float4 a = *(const float4*)(tb + kk * 32);
        const float4 w = *(const float4*)(wb + kk * 129);
        FMA16(a, w, acc)
      }
    }
  }
  __syncthreads();

#pragma unroll
  for (int j = 0; j < 4; ++j) {
    const float bb = b1[oq4 + j];
    float4 v;
    v.x = silu_f(acc[0][j] + bb);
    v.y = silu_f(acc[1][j] + bb);
    v.z = silu_f(acc[2][j] + bb);
    v.w = silu_f(acc[3][j] + bb);
    const int o = oq4 + j;
    *(float4*)&Tt[o * 32 + (eq4 ^ (((o >> 2) & 7) << 2))] = v;
  }

  float acc2[4][4] = {};
  for (int kb = 0; kb < 128; kb += 32) {
    __syncthreads();
    for (int i = tid; i < 4096; i += 256) {
      const int kk = i & 31, o = i >> 5;
      Wt[kk * 129 + o] = w2[(size_t)o * 128 + kb + kk];
    }
    __syncthreads();
#pragma unroll
    for (int q = 0; q < 8; ++q) {
      const int S = q << 2;
      const float* tb = &Tt[(kb + q * 4) * 32 + (eq4 ^ S)];
      const float* wb = &Wt[(q * 4) * 129 + oq4];
#pragma unroll
      for (int kk = 0; kk < 4; ++kk) {
        const float4 a = *(const float4*)(tb + kk * 32);
        const float4 w = *(const float4*)(wb + kk * 129);
        FMA16(a, w, acc2)
      }
    }
  }

  const float4 bb = *(const float4*)(b2 + oq4);
#pragma unroll
  for (int i = 0; i < 4; ++i) {
    const int node = nbase + eq4 + i;
    if (node < N_NODES) {
      const float4 r = *(const float4*)(hn + (size_t)node * DIM + oq4);
      float4 o;
      o.x = r.x + acc2[i][0] + bb.x;
      o.y = r.y + acc2[i][1] + bb.y;
      o.z = r.z + acc2[i][2] + bb.z;
      o.w = r.w + acc2[i][3] + bb.w;
      *(float4*)(out + (size_t)node * DIM + oq4) = o;
    }
  }
}

// ---------------- e passthrough (as float values) ----------------
__global__ void ecopy_kernel(const int* __restrict__ e, float* __restrict__ out_e) {
  const int i4 = blockIdx.x * blockDim.x + threadIdx.x;
  if (i4 >= 2 * N_EDGES / 4) return;
  const int4 v = ((const int4*)e)[i4];
  float4 o;
  o.x = (float)v.x;
  o.y = (float)v.y;
  o.z = (float)v.z;
  o.w = (float)v.w;
  ((float4*)out_e)[i4] = o;
}

extern "C" void kernel_launch(void* const* d_in, const int* in_sizes, int n_in, void* d_out,
                              int out_size, void* d_ws, size_t ws_size, hipStream_t stream) {
  const float* h = (const float*)d_in[0];
  const float* x = (const float*)d_in[1];
  const int* e = (const int*)d_in[2];
  const float* bn_gamma = (const float*)d_in[3];
  const float* bn_beta = (const float*)d_in[4];
  const float* fe_w1 = (const float*)d_in[5];
  const float* fe_b1 = (const float*)d_in[6];
  const float* fe_w2 = (const float*)d_in[7];
  const float* fe_b2 = (const float*)d_in[8];
  const float* finf_w = (const float*)d_in[9];
  const float* finf_b = (const float*)d_in[10];
  const float* fh_w1 = (const float*)d_in[11];
  const float* fh_b1 = (const float*)d_in[12];
  const float* fh_w2 = (const float*)d_in[13];
  const float* fh_b2 = (const float*)d_in[14];

  float* ws = (float*)d_ws;
  float* h_norm = ws;                                 // 6.4M floats
  float* m_i = ws + (size_t)N_NODES * DIM;            // 6.4M floats
  float* stats = ws + 2 * (size_t)N_NODES * DIM;      // sums[256] + scale[128] + shift[128]

  float* out = (float*)d_out;
  float* out_e = out + (size_t)N_NODES * DIM;

  hipMemsetAsync(stats, 0, 512 * sizeof(float), stream);
  hipMemsetAsync(m_i, 0, (size_t)N_NODES * DIM * sizeof(float), stream);

  bn_stats_kernel<<<256, 256, 0, stream>>>(h, stats);
  bn_finalize_kernel<<<1, 128, 0, stream>>>(stats, bn_gamma, bn_beta);
  bn_apply_kernel<<<(N_NODES * DIM / 4 + 255) / 256, 256, 0, stream>>>(h, stats, h_norm);
  edge_kernel<<<N_EDGES / ET, 256, 0, stream>>>(h_norm, x, e, fe_w1, fe_b1, fe_w2, fe_b2, finf_w,
                                                finf_b, m_i);
  node_kernel<<<(N_NODES + ET - 1) / ET, 256, 0, stream>>>(h_norm, m_i, fh_w1, fh_b1, fh_w2, fh_b2,
                                                           out);
  ecopy_kernel<<<(2 * N_EDGES / 4 + 255) / 256, 256, 0, stream>>>(e, out_e);
}

// Round 3
// 682.860 us; speedup vs baseline: 6.1180x; 6.1180x over previous
//
#include <hip/hip_runtime.h>
#include <math.h>

#define N_NODES 50000
#define N_EDGES 800000
#define DIM 128
#define EB 64  // edges/nodes per block in the MFMA kernels

typedef __attribute__((ext_vector_type(8))) short short8v;  // 8 bf16 = 4 VGPRs
typedef __attribute__((ext_vector_type(4))) float f32x4;

__device__ __forceinline__ float silu_f(float v) { return v / (1.f + __expf(-v)); }

__device__ __forceinline__ unsigned short f2bf(float f) {
  unsigned u = __float_as_uint(f);
  return (unsigned short)((u + 0x7fffu + ((u >> 16) & 1u)) >> 16);
}

// ---------------- BatchNorm ----------------
__global__ void bn_stats_kernel(const float* __restrict__ h, float* __restrict__ stats) {
  const int c = threadIdx.x & 127;
  const int rs = threadIdx.x >> 7;
  float s = 0.f, s2 = 0.f;
  for (int row = blockIdx.x * 2 + rs; row < N_NODES; row += gridDim.x * 2) {
    float v = h[(size_t)row * DIM + c];
    s += v;
    s2 += v * v;
  }
  __shared__ float red[256];
  red[threadIdx.x] = s;
  __syncthreads();
  if (threadIdx.x < 128) atomicAdd(&stats[c], red[c] + red[c + 128]);
  __syncthreads();
  red[threadIdx.x] = s2;
  __syncthreads();
  if (threadIdx.x < 128) atomicAdd(&stats[DIM + c], red[c] + red[c + 128]);
}

__global__ void bn_finalize_kernel(float* __restrict__ stats, const float* __restrict__ gamma,
                                   const float* __restrict__ beta) {
  const int c = threadIdx.x;  // 128 threads
  const float inv_n = 1.f / (float)N_NODES;
  float mean = stats[c] * inv_n;
  float var = stats[DIM + c] * inv_n - mean * mean;
  float s = gamma[c] * rsqrtf(var + 1e-5f);
  stats[2 * DIM + c] = s;                   // scale
  stats[3 * DIM + c] = beta[c] - mean * s;  // shift
}

// normalized h in bf16 (for MFMA A operands)
__global__ void bn_apply_bf_kernel(const float* __restrict__ h, const float* __restrict__ stats,
                                   unsigned short* __restrict__ hbf) {
  const int i4 = blockIdx.x * blockDim.x + threadIdx.x;
  if (i4 >= N_NODES * DIM / 4) return;
  const int c4 = i4 & 31;
  const float4 v = ((const float4*)h)[i4];
  const float4 a = ((const float4*)(stats + 2 * DIM))[c4];
  const float4 b = ((const float4*)(stats + 3 * DIM))[c4];
  ushort4 o;
  o.x = f2bf(v.x * a.x + b.x);
  o.y = f2bf(v.y * a.y + b.y);
  o.z = f2bf(v.z * a.z + b.z);
  o.w = f2bf(v.w * a.w + b.w);
  ((ushort4*)hbf)[i4] = o;
}

// ---------------- weight prep (fp32 -> bf16, contiguous strides) ----------------
__global__ void prep_weights_kernel(const float* __restrict__ fe_w1, const float* __restrict__ fe_w2,
                                    const float* __restrict__ fh_w1, const float* __restrict__ fh_w2,
                                    unsigned short* __restrict__ w1bf, float* __restrict__ w1col,
                                    unsigned short* __restrict__ w2bf, unsigned short* __restrict__ fw1bf,
                                    unsigned short* __restrict__ fw2bf) {
  int idx = blockIdx.x * blockDim.x + threadIdx.x;
  if (idx < 32768) {  // w1bf[o][k], k<256 of the 257
    int o = idx >> 8, k = idx & 255;
    w1bf[idx] = f2bf(fe_w1[(size_t)o * 257 + k]);
    return;
  }
  idx -= 32768;
  if (idx < 128) { w1col[idx] = fe_w1[(size_t)idx * 257 + 256]; return; }
  idx -= 128;
  if (idx < 16384) { w2bf[idx] = f2bf(fe_w2[idx]); return; }
  idx -= 16384;
  if (idx < 32768) { fw1bf[idx] = f2bf(fh_w1[idx]); return; }
  idx -= 32768;
  if (idx < 16384) { fw2bf[idx] = f2bf(fh_w2[idx]); return; }
}

// ---------------- CSR build (counting sort by src) ----------------
__global__ void hist_kernel(const int* __restrict__ e, int* __restrict__ cnt) {
  int i = blockIdx.x * blockDim.x + threadIdx.x;
  if (i < N_EDGES) atomicAdd(&cnt[e[i]], 1);
}

__global__ void scan_kernel(int* __restrict__ cnt, int* __restrict__ start) {
  // single block, 1024 threads; 49 elems each (49*1024 >= 50000)
  __shared__ int part[1024];
  const int t = threadIdx.x;
  const int base = t * 49;
  int s = 0;
  for (int j = 0; j < 49; ++j) {
    int i = base + j;
    if (i < N_NODES) s += cnt[i];
  }
  part[t] = s;
  __syncthreads();
  for (int off = 1; off < 1024; off <<= 1) {
    int v = (t >= off) ? part[t - off] : 0;
    __syncthreads();
    part[t] += v;
    __syncthreads();
  }
  int run = (t > 0) ? part[t - 1] : 0;
  for (int j = 0; j < 49; ++j) {
    int i = base + j;
    if (i < N_NODES) {
      int c = cnt[i];
      start[i] = run;
      cnt[i] = run;  // becomes the scatter cursor
      run += c;
    }
  }
  if (t == 1023) start[N_NODES] = part[1023];
}

__global__ void scatter_kernel(const int* __restrict__ e, int* __restrict__ cursor,
                               int* __restrict__ perm) {
  int i = blockIdx.x * blockDim.x + threadIdx.x;
  if (i >= N_EDGES) return;
  int s = e[i];
  int pos = atomicAdd(&cursor[s], 1);
  perm[pos] = i;
}

// ---------------- edge MLP + gate + local segmented aggregation ----------------
__launch_bounds__(256, 2)
__global__ void edge_mfma_kernel(const unsigned short* __restrict__ hbf, const float* __restrict__ x,
                                 const int* __restrict__ e, const int* __restrict__ perm,
                                 const unsigned short* __restrict__ w1bf, const float* __restrict__ w1col,
                                 const float* __restrict__ b1, const unsigned short* __restrict__ w2bf,
                                 const float* __restrict__ b2, const float* __restrict__ winf,
                                 const float* __restrict__ binf, float* __restrict__ mi_g) {
  __shared__ unsigned short Abuf[EB * 256];  // 32 KB; GEMM1 A (swizzled); later fp32 gated-msg tile
  __shared__ unsigned short A2[EB * 128];    // 16 KB; GEMM2 A (swizzled)
  __shared__ float dists[EB];
  __shared__ int srcs[EB], dsts[EB];
  __shared__ float gbuf[EB][5];
  __shared__ float gate[EB];

  const int tid = threadIdx.x;
  const int l = tid & 63, w = tid >> 6;
  const int r16 = l & 15, g = l >> 4;
  const int ebase = blockIdx.x * EB;

  if (tid < EB) {
    const int eid = perm[ebase + tid];
    const int s = e[eid], d = e[N_EDGES + eid];
    srcs[tid] = s;
    dsts[tid] = d;
    const float dx = x[s * 3 + 0] - x[d * 3 + 0];
    const float dy = x[s * 3 + 1] - x[d * 3 + 1];
    const float dz = x[s * 3 + 2] - x[d * 3 + 2];
    dists[tid] = sqrtf(dx * dx + dy * dy + dz * dz);
  }
  __syncthreads();

  // stage A[e][k] bf16: k<128 = h[src], 128..255 = h[dst]; 16B chunks XOR-swizzled
  {
    const int er = tid >> 2, cb = (tid & 3) * 8;
    const unsigned short* ps = hbf + (size_t)srcs[er] * DIM;
    const unsigned short* pd = hbf + (size_t)dsts[er] * DIM;
#pragma unroll
    for (int j = 0; j < 8; ++j) {
      const int c = cb + j;  // chunk 0..31 (8 elems each)
      const int4 v = (c < 16) ? *(const int4*)(ps + c * 8) : *(const int4*)(pd + (c - 16) * 8);
      *(int4*)&Abuf[er * 256 + ((c ^ (er & 7)) << 3)] = v;
    }
  }
  __syncthreads();

  // ---- GEMM1: D[64 e][128 o] = A[64][256] x W1^T, K=256 via MFMA ----
  f32x4 acc[4][2];
#pragma unroll
  for (int m_ = 0; m_ < 4; ++m_)
#pragma unroll
    for (int ni = 0; ni < 2; ++ni) acc[m_][ni] = (f32x4){0.f, 0.f, 0.f, 0.f};

  for (int kb = 0; kb < 8; ++kb) {
    short8v a[4], b[2];
#pragma unroll
    for (int m_ = 0; m_ < 4; ++m_) {
      const int er = m_ * 16 + r16;
      const int chunk = kb * 4 + g;
      a[m_] = *(const short8v*)&Abuf[er * 256 + ((chunk ^ (er & 7)) << 3)];
    }
#pragma unroll
    for (int ni = 0; ni < 2; ++ni) {
      const int o = w * 32 + ni * 16 + r16;
      b[ni] = *(const short8v*)&w1bf[o * 256 + kb * 32 + g * 8];
    }
#pragma unroll
    for (int m_ = 0; m_ < 4; ++m_)
#pragma unroll
      for (int ni = 0; ni < 2; ++ni)
        acc[m_][ni] = __builtin_amdgcn_mfma_f32_16x16x32_bf16(a[m_], b[ni], acc[m_][ni], 0, 0, 0);
  }

  // tail k=256 (dist column, fp32 rank-1) + bias + SiLU -> A2 (swizzled bf16)
#pragma unroll
  for (int ni = 0; ni < 2; ++ni) {
    const int o = w * 32 + ni * 16 + r16;
    const float wc = w1col[o];
    const float bb = b1[o];
#pragma unroll
    for (int m_ = 0; m_ < 4; ++m_)
#pragma unroll
      for (int r = 0; r < 4; ++r) {
        const int er = m_ * 16 + g * 4 + r;
        const float v = silu_f(acc[m_][ni][r] + dists[er] * wc + bb);
        A2[er * 128 + (o ^ ((er & 7) << 3))] = f2bf(v);
      }
  }
  __syncthreads();

  // ---- GEMM2: K=128 ----
  f32x4 acc2[4][2];
#pragma unroll
  for (int m_ = 0; m_ < 4; ++m_)
#pragma unroll
    for (int ni = 0; ni < 2; ++ni) acc2[m_][ni] = (f32x4){0.f, 0.f, 0.f, 0.f};

  for (int kb = 0; kb < 4; ++kb) {
    short8v a[4], b[2];
    const int k0 = kb * 32 + g * 8;
#pragma unroll
    for (int m_ = 0; m_ < 4; ++m_) {
      const int er = m_ * 16 + r16;
      a[m_] = *(const short8v*)&A2[er * 128 + (k0 ^ ((er & 7) << 3))];
    }
#pragma unroll
    for (int ni = 0; ni < 2; ++ni) {
      const int o = w * 32 + ni * 16 + r16;
      b[ni] = *(const short8v*)&w2bf[o * 128 + k0];
    }
#pragma unroll
    for (int m_ = 0; m_ < 4; ++m_)
#pragma unroll
      for (int ni = 0; ni < 2; ++ni)
        acc2[m_][ni] = __builtin_amdgcn_mfma_f32_16x16x32_bf16(a[m_], b[ni], acc2[m_][ni], 0, 0, 0);
  }

  // ---- bias + SiLU -> m2; gate partials ----
  float m2v[4][2][4];
  float p[4][4];
#pragma unroll
  for (int m_ = 0; m_ < 4; ++m_)
#pragma unroll
    for (int r = 0; r < 4; ++r) p[m_][r] = 0.f;

#pragma unroll
  for (int ni = 0; ni < 2; ++ni) {
    const int o = w * 32 + ni * 16 + r16;
    const float bb = b2[o];
    const float wf = winf[o];
#pragma unroll
    for (int m_ = 0; m_ < 4; ++m_)
#pragma unroll
      for (int r = 0; r < 4; ++r) {
        const float v = silu_f(acc2[m_][ni][r] + bb);
        m2v[m_][ni][r] = v;
        p[m_][r] += v * wf;
      }
  }
  // reduce gate partials across the 16 lanes of each group
#pragma unroll
  for (int msk = 1; msk < 16; msk <<= 1)
#pragma unroll
    for (int m_ = 0; m_ < 4; ++m_)
#pragma unroll
      for (int r = 0; r < 4; ++r) p[m_][r] += __shfl_xor(p[m_][r], msk, 64);
  if (r16 == 0) {
#pragma unroll
    for (int m_ = 0; m_ < 4; ++m_)
#pragma unroll
      for (int r = 0; r < 4; ++r) gbuf[m_ * 16 + g * 4 + r][w] = p[m_][r];
  }
  __syncthreads();
  if (tid < EB) {
    const float s = gbuf[tid][0] + gbuf[tid][1] + gbuf[tid][2] + gbuf[tid][3] + binf[0];
    gate[tid] = 1.f / (1.f + __expf(-s));
  }
  __syncthreads();

  // ---- gated messages -> LDS fp32 tile (aliases Abuf), lightly swizzled ----
  float* Mf = (float*)Abuf;
#pragma unroll
  for (int ni = 0; ni < 2; ++ni) {
    const int o = w * 32 + ni * 16 + r16;
#pragma unroll
    for (int m_ = 0; m_ < 4; ++m_)
#pragma unroll
      for (int r = 0; r < 4; ++r) {
        const int er = m_ * 16 + g * 4 + r;
        Mf[er * 128 + (o ^ ((er & 7) << 2))] = m2v[m_][ni][r] * gate[er];
      }
  }
  __syncthreads();

  // ---- segmented column reduction over sorted srcs; one atomic per run ----
  {
    const int c = tid & 127;
    const int r0 = (tid >> 7) * 32;
    int cur = srcs[r0];
    float a = 0.f;
    for (int row = r0; row < r0 + 32; ++row) {
      const int s = srcs[row];  // wave-uniform
      if (s != cur) {
        atomicAdd(&mi_g[(size_t)cur * DIM + c], a);
        a = 0.f;
        cur = s;
      }
      a += Mf[row * 128 + (c ^ ((row & 7) << 2))];
    }
    atomicAdd(&mi_g[(size_t)cur * DIM + c], a);
  }
}

// ---------------- node MLP (MFMA) + residual ----------------
__launch_bounds__(256, 2)
__global__ void node_mfma_kernel(const unsigned short* __restrict__ hbf,
                                 const float* __restrict__ mi_g,
                                 const float* __restrict__ h, const float* __restrict__ stats,
                                 const unsigned short* __restrict__ fw1, const float* __restrict__ fb1,
                                 const unsigned short* __restrict__ fw2, const float* __restrict__ fb2,
                                 float* __restrict__ out) {
  __shared__ unsigned short Abuf[EB * 256];
  __shared__ unsigned short A2[EB * 128];

  const int tid = threadIdx.x;
  const int l = tid & 63, w = tid >> 6;
  const int r16 = l & 15, g = l >> 4;
  const int nbase = blockIdx.x * EB;

  {
    const int er = tid >> 2, cb = (tid & 3) * 8;
    int n = nbase + er;
    if (n >= N_NODES) n = N_NODES - 1;
    const unsigned short* ps = hbf + (size_t)n * DIM;
    const float* pm = mi_g + (size_t)n * DIM;
#pragma unroll
    for (int j = 0; j < 8; ++j) {
      const int c = cb + j;
      int4 v;
      if (c < 16) {
        v = *(const int4*)(ps + c * 8);
      } else {
        const float4 f0 = *(const float4*)(pm + (c - 16) * 8);
        const float4 f1 = *(const float4*)(pm + (c - 16) * 8 + 4);
        v.x = (int)f2bf(f0.x) | ((int)f2bf(f0.y) << 16);
        v.y = (int)f2bf(f0.z) | ((int)f2bf(f0.w) << 16);
        v.z = (int)f2bf(f1.x) | ((int)f2bf(f1.y) << 16);
        v.w = (int)f2bf(f1.z) | ((int)f2bf(f1.w) << 16);
      }
      *(int4*)&Abuf[er * 256 + ((c ^ (er & 7)) << 3)] = v;
    }
  }
  __syncthreads();

  f32x4 acc[4][2];
#pragma unroll
  for (int m_ = 0; m_ < 4; ++m_)
#pragma unroll
    for (int ni = 0; ni < 2; ++ni) acc[m_][ni] = (f32x4){0.f, 0.f, 0.f, 0.f};

  for (int kb = 0; kb < 8; ++kb) {
    short8v a[4], b[2];
#pragma unroll
    for (int m_ = 0; m_ < 4; ++m_) {
      const int er = m_ * 16 + r16;
      const int chunk = kb * 4 + g;
      a[m_] = *(const short8v*)&Abuf[er * 256 + ((chunk ^ (er & 7)) << 3)];
    }
#pragma unroll
    for (int ni = 0; ni < 2; ++ni) {
      const int o = w * 32 + ni * 16 + r16;
      b[ni] = *(const short8v*)&fw1[o * 256 + kb * 32 + g * 8];
    }
#pragma unroll
    for (int m_ = 0; m_ < 4; ++m_)
#pragma unroll
      for (int ni = 0; ni < 2; ++ni)
        acc[m_][ni] = __builtin_amdgcn_mfma_f32_16x16x32_bf16(a[m_], b[ni], acc[m_][ni], 0, 0, 0);
  }

#pragma unroll
  for (int ni = 0; ni < 2; ++ni) {
    const int o = w * 32 + ni * 16 + r16;
    const float bb = fb1[o];
#pragma unroll
    for (int m_ = 0; m_ < 4; ++m_)
#pragma unroll
      for (int r = 0; r < 4; ++r) {
        const int er = m_ * 16 + g * 4 + r;
        A2[er * 128 + (o ^ ((er & 7) << 3))] = f2bf(silu_f(acc[m_][ni][r] + bb));
      }
  }
  __syncthreads();

  f32x4 acc2[4][2];
#pragma unroll
  for (int m_ = 0; m_ < 4; ++m_)
#pragma unroll
    for (int ni = 0; ni < 2; ++ni) acc2[m_][ni] = (f32x4){0.f, 0.f, 0.f, 0.f};

  for (int kb = 0; kb < 4; ++kb) {
    short8v a[4], b[2];
    const int k0 = kb * 32 + g * 8;
#pragma unroll
    for (int m_ = 0; m_ < 4; ++m_) {
      const int er = m_ * 16 + r16;
      a[m_] = *(const short8v*)&A2[er * 128 + (k0 ^ ((er & 7) << 3))];
    }
#pragma unroll
    for (int ni = 0; ni < 2; ++ni) {
      const int o = w * 32 + ni * 16 + r16;
      b[ni] = *(const short8v*)&fw2[o * 128 + k0];
    }
#pragma unroll
    for (int m_ = 0; m_ < 4; ++m_)
#pragma unroll
      for (int ni = 0; ni < 2; ++ni)
        acc2[m_][ni] = __builtin_amdgcn_mfma_f32_16x16x32_bf16(a[m_], b[ni], acc2[m_][ni], 0, 0, 0);
  }

  // epilogue: out = BN(h) + update   (BN recomputed in fp32 from h and stats)
#pragma unroll
  for (int ni = 0; ni < 2; ++ni) {
    const int o = w * 32 + ni * 16 + r16;
    const float bb = fb2[o];
    const float sc = stats[2 * DIM + o];
    const float sh = stats[3 * DIM + o];
#pragma unroll
    for (int m_ = 0; m_ < 4; ++m_)
#pragma unroll
      for (int r = 0; r < 4; ++r) {
        const int n = nbase + m_ * 16 + g * 4 + r;
        if (n < N_NODES) {
          const float hv = h[(size_t)n * DIM + o];
          out[(size_t)n * DIM + o] = hv * sc + sh + acc2[m_][ni][r] + bb;
        }
      }
  }
}

// ---------------- e passthrough (as float values) ----------------
__global__ void ecopy_kernel(const int* __restrict__ e, float* __restrict__ out_e) {
  const int i4 = blockIdx.x * blockDim.x + threadIdx.x;
  if (i4 >= 2 * N_EDGES / 4) return;
  const int4 v = ((const int4*)e)[i4];
  float4 o;
  o.x = (float)v.x;
  o.y = (float)v.y;
  o.z = (float)v.z;
  o.w = (float)v.w;
  ((float4*)out_e)[i4] = o;
}

extern "C" void kernel_launch(void* const* d_in, const int* in_sizes, int n_in, void* d_out,
                              int out_size, void* d_ws, size_t ws_size, hipStream_t stream) {
  const float* h = (const float*)d_in[0];
  const float* x = (const float*)d_in[1];
  const int* e = (const int*)d_in[2];
  const float* bn_gamma = (const float*)d_in[3];
  const float* bn_beta = (const float*)d_in[4];
  const float* fe_w1 = (const float*)d_in[5];
  const float* fe_b1 = (const float*)d_in[6];
  const float* fe_w2 = (const float*)d_in[7];
  const float* fe_b2 = (const float*)d_in[8];
  const float* finf_w = (const float*)d_in[9];
  const float* finf_b = (const float*)d_in[10];
  const float* fh_w1 = (const float*)d_in[11];
  const float* fh_b1 = (const float*)d_in[12];
  const float* fh_w2 = (const float*)d_in[13];
  const float* fh_b2 = (const float*)d_in[14];

  char* wp = (char*)d_ws;
  auto alloc = [&](size_t bytes) -> char* {
    char* p = wp;
    wp += (bytes + 255) & ~(size_t)255;
    return p;
  };
  float* stats = (float*)alloc(512 * sizeof(float));
  unsigned short* hbf = (unsigned short*)alloc((size_t)N_NODES * DIM * 2);
  unsigned short* w1bf = (unsigned short*)alloc(128 * 256 * 2);
  float* w1col = (float*)alloc(128 * 4);
  unsigned short* w2bf = (unsigned short*)alloc(128 * 128 * 2);
  unsigned short* fw1bf = (unsigned short*)alloc(128 * 256 * 2);
  unsigned short* fw2bf = (unsigned short*)alloc(128 * 128 * 2);
  int* cnt = (int*)alloc((size_t)(N_NODES + 1) * 4);  // doubles as scatter cursor
  int* startp = (int*)alloc((size_t)(N_NODES + 1) * 4);
  int* perm = (int*)alloc((size_t)N_EDGES * 4);
  float* mi_g = (float*)alloc((size_t)N_NODES * DIM * 4);

  float* out = (float*)d_out;
  float* out_e = out + (size_t)N_NODES * DIM;

  hipMemsetAsync(stats, 0, 512 * sizeof(float), stream);
  hipMemsetAsync(cnt, 0, (N_NODES + 1) * sizeof(int), stream);
  hipMemsetAsync(mi_g, 0, (size_t)N_NODES * DIM * sizeof(float), stream);

  bn_stats_kernel<<<256, 256, 0, stream>>>(h, stats);
  bn_finalize_kernel<<<1, 128, 0, stream>>>(stats, bn_gamma, bn_beta);
  bn_apply_bf_kernel<<<(N_NODES * DIM / 4 + 255) / 256, 256, 0, stream>>>(h, stats, hbf);
  prep_weights_kernel<<<(98432 + 255) / 256, 256, 0, stream>>>(fe_w1, fe_w2, fh_w1, fh_w2, w1bf,
                                                               w1col, w2bf, fw1bf, fw2bf);
  hist_kernel<<<(N_EDGES + 255) / 256, 256, 0, stream>>>(e, cnt);
  scan_kernel<<<1, 1024, 0, stream>>>(cnt, startp);
  scatter_kernel<<<(N_EDGES + 255) / 256, 256, 0, stream>>>(e, cnt, perm);

  edge_mfma_kernel<<<N_EDGES / EB, 256, 0, stream>>>(hbf, x, e, perm, w1bf, w1col, fe_b1, w2bf,
                                                     fe_b2, finf_w, finf_b, mi_g);
  node_mfma_kernel<<<(N_NODES + EB - 1) / EB, 256, 0, stream>>>(hbf, mi_g, h, stats, fw1bf, fh_b1,
                                                                fw2bf, fh_b2, out);
  ecopy_kernel<<<(2 * N_EDGES / 4 + 255) / 256, 256, 0, stream>>>(e, out_e);
}

// Round 4
// 492.640 us; speedup vs baseline: 8.4804x; 1.3861x over previous
//
#include <hip/hip_runtime.h>
#include <math.h>

#define N_NODES 50000
#define N_EDGES 800000
#define DIM 128
#define EB 64       // edges/nodes per block in the MFMA kernels
#define SCAN_B 196  // ceil(N_NODES/256)

typedef __attribute__((ext_vector_type(8))) short short8v;  // 8 bf16 = 4 VGPRs
typedef __attribute__((ext_vector_type(4))) float f32x4;

__device__ __forceinline__ float silu_f(float v) { return __fdividef(v, 1.f + __expf(-v)); }

__device__ __forceinline__ unsigned short f2bf(float f) {
  unsigned u = __float_as_uint(f);
  return (unsigned short)((u + 0x7fffu + ((u >> 16) & 1u)) >> 16);
}

// ---------------- BatchNorm ----------------
__global__ void bn_stats_kernel(const float* __restrict__ h, float* __restrict__ stats) {
  const int c = threadIdx.x & 127;
  const int rs = threadIdx.x >> 7;
  float s = 0.f, s2 = 0.f;
  for (int row = blockIdx.x * 2 + rs; row < N_NODES; row += gridDim.x * 2) {
    float v = h[(size_t)row * DIM + c];
    s += v;
    s2 += v * v;
  }
  __shared__ float red[256];
  red[threadIdx.x] = s;
  __syncthreads();
  if (threadIdx.x < 128) atomicAdd(&stats[c], red[c] + red[c + 128]);
  __syncthreads();
  red[threadIdx.x] = s2;
  __syncthreads();
  if (threadIdx.x < 128) atomicAdd(&stats[DIM + c], red[c] + red[c + 128]);
}

__global__ void bn_finalize_kernel(float* __restrict__ stats, const float* __restrict__ gamma,
                                   const float* __restrict__ beta) {
  const int c = threadIdx.x;  // 128 threads
  const float inv_n = 1.f / (float)N_NODES;
  float mean = stats[c] * inv_n;
  float var = stats[DIM + c] * inv_n - mean * mean;
  float s = gamma[c] * rsqrtf(var + 1e-5f);
  stats[2 * DIM + c] = s;                   // scale
  stats[3 * DIM + c] = beta[c] - mean * s;  // shift
}

__global__ void bn_apply_bf_kernel(const float* __restrict__ h, const float* __restrict__ stats,
                                   unsigned short* __restrict__ hbf) {
  const int i4 = blockIdx.x * blockDim.x + threadIdx.x;
  if (i4 >= N_NODES * DIM / 4) return;
  const int c4 = i4 & 31;
  const float4 v = ((const float4*)h)[i4];
  const float4 a = ((const float4*)(stats + 2 * DIM))[c4];
  const float4 b = ((const float4*)(stats + 3 * DIM))[c4];
  ushort4 o;
  o.x = f2bf(v.x * a.x + b.x);
  o.y = f2bf(v.y * a.y + b.y);
  o.z = f2bf(v.z * a.z + b.z);
  o.w = f2bf(v.w * a.w + b.w);
  ((ushort4*)hbf)[i4] = o;
}

// ---------------- weight prep (fp32 -> bf16, contiguous strides) ----------------
__global__ void prep_weights_kernel(const float* __restrict__ fe_w1, const float* __restrict__ fe_w2,
                                    const float* __restrict__ fh_w1, const float* __restrict__ fh_w2,
                                    unsigned short* __restrict__ w1bf, float* __restrict__ w1col,
                                    unsigned short* __restrict__ w2bf, unsigned short* __restrict__ fw1bf,
                                    unsigned short* __restrict__ fw2bf) {
  int idx = blockIdx.x * blockDim.x + threadIdx.x;
  if (idx < 32768) {  // w1bf[o][k], k<256 of the 257
    int o = idx >> 8, k = idx & 255;
    w1bf[idx] = f2bf(fe_w1[(size_t)o * 257 + k]);
    return;
  }
  idx -= 32768;
  if (idx < 128) { w1col[idx] = fe_w1[(size_t)idx * 257 + 256]; return; }
  idx -= 128;
  if (idx < 16384) { w2bf[idx] = f2bf(fe_w2[idx]); return; }
  idx -= 16384;
  if (idx < 32768) { fw1bf[idx] = f2bf(fh_w1[idx]); return; }
  idx -= 32768;
  if (idx < 16384) { fw2bf[idx] = f2bf(fh_w2[idx]); return; }
}

// ---------------- CSR build (counting sort by src, hierarchical scan) ----------------
__global__ void hist_kernel(const int* __restrict__ e, int* __restrict__ cnt) {
  int i = blockIdx.x * blockDim.x + threadIdx.x;
  if (i < N_EDGES) atomicAdd(&cnt[e[i]], 1);
}

__global__ void scanA_kernel(const int* __restrict__ cnt, int* __restrict__ bsum) {
  __shared__ int red[256];
  const int t = threadIdx.x;
  const int i = blockIdx.x * 256 + t;
  red[t] = (i < N_NODES) ? cnt[i] : 0;
  __syncthreads();
  for (int off = 128; off > 0; off >>= 1) {
    if (t < off) red[t] += red[t + off];
    __syncthreads();
  }
  if (t == 0) bsum[blockIdx.x] = red[0];
}

__global__ void scanB_kernel(int* __restrict__ bsum) {
  __shared__ int s[256];
  const int t = threadIdx.x;
  const int v = (t < SCAN_B) ? bsum[t] : 0;
  s[t] = v;
  __syncthreads();
  for (int off = 1; off < 256; off <<= 1) {
    const int add = (t >= off) ? s[t - off] : 0;
    __syncthreads();
    s[t] += add;
    __syncthreads();
  }
  if (t < SCAN_B) bsum[t] = s[t] - v;  // exclusive block prefix
}

__global__ void scanC_kernel(const int* __restrict__ cnt, const int* __restrict__ bsum,
                             int* __restrict__ cursor) {
  __shared__ int s[256];
  const int t = threadIdx.x;
  const int i = blockIdx.x * 256 + t;
  const int v = (i < N_NODES) ? cnt[i] : 0;
  s[t] = v;
  __syncthreads();
  for (int off = 1; off < 256; off <<= 1) {
    const int add = (t >= off) ? s[t - off] : 0;
    __syncthreads();
    s[t] += add;
    __syncthreads();
  }
  if (i < N_NODES) cursor[i] = bsum[blockIdx.x] + s[t] - v;
}

// scatter edges into sorted-by-src arrays; compute dist once here
__global__ void sort_scatter_kernel(const int* __restrict__ e, const float* __restrict__ x,
                                    int* __restrict__ cursor, int* __restrict__ srcS,
                                    int* __restrict__ dstS, float* __restrict__ distS) {
  const int i = blockIdx.x * blockDim.x + threadIdx.x;
  if (i >= N_EDGES) return;
  const int s = e[i], d = e[N_EDGES + i];
  const float dx = x[s * 3 + 0] - x[d * 3 + 0];
  const float dy = x[s * 3 + 1] - x[d * 3 + 1];
  const float dz = x[s * 3 + 2] - x[d * 3 + 2];
  const int pos = atomicAdd(&cursor[s], 1);
  srcS[pos] = s;
  dstS[pos] = d;
  distS[pos] = sqrtf(dx * dx + dy * dy + dz * dz);
}

// ---------------- edge MLP + gate + local segmented aggregation ----------------
__launch_bounds__(256, 4)
__global__ void edge_mfma_kernel(const unsigned short* __restrict__ hbf,
                                 const int* __restrict__ srcS, const int* __restrict__ dstS,
                                 const float* __restrict__ distS,
                                 const unsigned short* __restrict__ w1bf, const float* __restrict__ w1col,
                                 const float* __restrict__ b1, const unsigned short* __restrict__ w2bf,
                                 const float* __restrict__ b2, const float* __restrict__ winf,
                                 const float* __restrict__ binf, float* __restrict__ mi_g) {
  // One 32 KB buffer, three lifetimes (barrier-separated):
  //   phase 1: Abuf bf16[64][256]  (GEMM1 A, swizzled)
  //   phase 2: A2   bf16[64][128]  (GEMM2 A, swizzled; first 16 KB)
  //   phase 3: Mf   f32 [64][128]  (gated messages, swizzled)
  __shared__ unsigned short Abuf[EB * 256];
  __shared__ int srcs[EB];
  __shared__ int dsts[EB];
  __shared__ float dists[EB];
  __shared__ float gbuf[EB][5];
  __shared__ float gate[EB];

  unsigned short* A2 = Abuf;
  float* Mf = (float*)Abuf;

  const int tid = threadIdx.x;
  const int l = tid & 63, w = tid >> 6;
  const int r16 = l & 15, g = l >> 4;
  const int ebase = blockIdx.x * EB;

  if (tid < EB) {
    srcs[tid] = srcS[ebase + tid];
    dsts[tid] = dstS[ebase + tid];
    dists[tid] = distS[ebase + tid];
  }
  __syncthreads();

  // stage A[e][k] bf16: k<128 = h[src], 128..255 = h[dst]; 16B chunks XOR-swizzled
  {
    const int er = tid >> 2, cb = (tid & 3) * 8;
    const unsigned short* ps = hbf + (size_t)srcs[er] * DIM;
    const unsigned short* pd = hbf + (size_t)dsts[er] * DIM;
#pragma unroll
    for (int j = 0; j < 8; ++j) {
      const int c = cb + j;  // chunk 0..31 (8 elems each)
      const int4 v = (c < 16) ? *(const int4*)(ps + c * 8) : *(const int4*)(pd + (c - 16) * 8);
      *(int4*)&Abuf[er * 256 + ((c ^ (er & 7)) << 3)] = v;
    }
  }
  __syncthreads();

  // ---- GEMM1: D[64 e][128 o] = A[64][256] x W1^T, K=256 via MFMA ----
  f32x4 acc[4][2];
#pragma unroll
  for (int m_ = 0; m_ < 4; ++m_)
#pragma unroll
    for (int ni = 0; ni < 2; ++ni) acc[m_][ni] = (f32x4){0.f, 0.f, 0.f, 0.f};

  for (int kb = 0; kb < 8; ++kb) {
    short8v a[4], b[2];
#pragma unroll
    for (int m_ = 0; m_ < 4; ++m_) {
      const int er = m_ * 16 + r16;
      const int chunk = kb * 4 + g;
      a[m_] = *(const short8v*)&Abuf[er * 256 + ((chunk ^ (er & 7)) << 3)];
    }
#pragma unroll
    for (int ni = 0; ni < 2; ++ni) {
      const int o = w * 32 + ni * 16 + r16;
      b[ni] = *(const short8v*)&w1bf[o * 256 + kb * 32 + g * 8];
    }
#pragma unroll
    for (int m_ = 0; m_ < 4; ++m_)
#pragma unroll
      for (int ni = 0; ni < 2; ++ni)
        acc[m_][ni] = __builtin_amdgcn_mfma_f32_16x16x32_bf16(a[m_], b[ni], acc[m_][ni], 0, 0, 0);
  }
  __syncthreads();  // all Abuf reads done; A2 region may be overwritten

  // tail k=256 (dist column, fp32 rank-1) + bias + SiLU -> A2 (swizzled bf16)
  {
    const int o0 = w * 32 + r16, o1 = o0 + 16;
    const float wc0 = w1col[o0], wc1 = w1col[o1];
    const float bb0 = b1[o0], bb1 = b1[o1];
#pragma unroll
    for (int m_ = 0; m_ < 4; ++m_)
#pragma unroll
      for (int r = 0; r < 4; ++r) {
        const int er = m_ * 16 + g * 4 + r;
        const float dd = dists[er];
        const float v0 = silu_f(acc[m_][0][r] + dd * wc0 + bb0);
        const float v1 = silu_f(acc[m_][1][r] + dd * wc1 + bb1);
        A2[er * 128 + (o0 ^ ((er & 7) << 3))] = f2bf(v0);
        A2[er * 128 + (o1 ^ ((er & 7) << 3))] = f2bf(v1);
      }
  }
  __syncthreads();

  // ---- GEMM2: K=128 ----
  f32x4 acc2[4][2];
#pragma unroll
  for (int m_ = 0; m_ < 4; ++m_)
#pragma unroll
    for (int ni = 0; ni < 2; ++ni) acc2[m_][ni] = (f32x4){0.f, 0.f, 0.f, 0.f};

  for (int kb = 0; kb < 4; ++kb) {
    short8v a[4], b[2];
    const int k0 = kb * 32 + g * 8;
#pragma unroll
    for (int m_ = 0; m_ < 4; ++m_) {
      const int er = m_ * 16 + r16;
      a[m_] = *(const short8v*)&A2[er * 128 + (k0 ^ ((er & 7) << 3))];
    }
#pragma unroll
    for (int ni = 0; ni < 2; ++ni) {
      const int o = w * 32 + ni * 16 + r16;
      b[ni] = *(const short8v*)&w2bf[o * 128 + k0];
    }
#pragma unroll
    for (int m_ = 0; m_ < 4; ++m_)
#pragma unroll
      for (int ni = 0; ni < 2; ++ni)
        acc2[m_][ni] = __builtin_amdgcn_mfma_f32_16x16x32_bf16(a[m_], b[ni], acc2[m_][ni], 0, 0, 0);
  }

  // ---- bias + SiLU -> m2; gate partials ----
  float m2v[4][2][4];
  float pv[16];
  {
    const int o0 = w * 32 + r16, o1 = o0 + 16;
    const float b20 = b2[o0], b21 = b2[o1];
    const float wf0 = winf[o0], wf1 = winf[o1];
#pragma unroll
    for (int m_ = 0; m_ < 4; ++m_)
#pragma unroll
      for (int r = 0; r < 4; ++r) {
        const float v0 = silu_f(acc2[m_][0][r] + b20);
        const float v1 = silu_f(acc2[m_][1][r] + b21);
        m2v[m_][0][r] = v0;
        m2v[m_][1][r] = v1;
        pv[m_ * 4 + r] = v0 * wf0 + v1 * wf1;
      }
  }

  // ---- reduce-scatter over the 16 lanes: 15 shfl instead of 64 ----
  // After round with mask m, kept index bit = (r16 & m); final lane r16 holds sum of pv[r16].
  {
    const bool s0 = r16 & 1;
#pragma unroll
    for (int j = 0; j < 8; ++j) {
      const float lo = pv[2 * j], hi = pv[2 * j + 1];
      const float other = __shfl_xor(s0 ? lo : hi, 1, 64);
      pv[j] = (s0 ? hi : lo) + other;
    }
    const bool s1 = r16 & 2;
#pragma unroll
    for (int j = 0; j < 4; ++j) {
      const float lo = pv[2 * j], hi = pv[2 * j + 1];
      const float other = __shfl_xor(s1 ? lo : hi, 2, 64);
      pv[j] = (s1 ? hi : lo) + other;
    }
    const bool s2 = r16 & 4;
#pragma unroll
    for (int j = 0; j < 2; ++j) {
      const float lo = pv[2 * j], hi = pv[2 * j + 1];
      const float other = __shfl_xor(s2 ? lo : hi, 4, 64);
      pv[j] = (s2 ? hi : lo) + other;
    }
    const bool s3 = r16 & 8;
    {
      const float lo = pv[0], hi = pv[1];
      const float other = __shfl_xor(s3 ? lo : hi, 8, 64);
      pv[0] = (s3 ? hi : lo) + other;
    }
    // lane (g, r16) now holds the w-partial row-sum for er below
    const int er = (r16 >> 2) * 16 + g * 4 + (r16 & 3);
    gbuf[er][w] = pv[0];
  }
  __syncthreads();
  if (tid < EB) {
    const float s = gbuf[tid][0] + gbuf[tid][1] + gbuf[tid][2] + gbuf[tid][3] + binf[0];
    gate[tid] = __fdividef(1.f, 1.f + __expf(-s));
  }
  __syncthreads();

  // ---- gated messages -> Mf fp32 tile (overwrites Abuf), lightly swizzled ----
  {
    const int o0 = w * 32 + r16, o1 = o0 + 16;
#pragma unroll
    for (int m_ = 0; m_ < 4; ++m_)
#pragma unroll
      for (int r = 0; r < 4; ++r) {
        const int er = m_ * 16 + g * 4 + r;
        const float gg = gate[er];
        Mf[er * 128 + (o0 ^ ((er & 7) << 2))] = m2v[m_][0][r] * gg;
        Mf[er * 128 + (o1 ^ ((er & 7) << 2))] = m2v[m_][1][r] * gg;
      }
  }
  __syncthreads();

  // ---- segmented column reduction over sorted srcs; one atomic per run ----
  {
    const int c = tid & 127;
    const int r0 = (tid >> 7) * 32;
    int cur = srcs[r0];
    float a = 0.f;
    for (int row = r0; row < r0 + 32; ++row) {
      const int s = srcs[row];  // wave-uniform
      if (s != cur) {
        atomicAdd(&mi_g[(size_t)cur * DIM + c], a);
        a = 0.f;
        cur = s;
      }
      a += Mf[row * 128 + (c ^ ((row & 7) << 2))];
    }
    atomicAdd(&mi_g[(size_t)cur * DIM + c], a);
  }
}

// ---------------- node MLP (MFMA) + residual ----------------
__launch_bounds__(256, 4)
__global__ void node_mfma_kernel(const unsigned short* __restrict__ hbf,
                                 const float* __restrict__ mi_g,
                                 const float* __restrict__ h, const float* __restrict__ stats,
                                 const unsigned short* __restrict__ fw1, const float* __restrict__ fb1,
                                 const unsigned short* __restrict__ fw2, const float* __restrict__ fb2,
                                 float* __restrict__ out) {
  __shared__ unsigned short Abuf[EB * 256];  // A2 aliases the first 16 KB
  unsigned short* A2 = Abuf;

  const int tid = threadIdx.x;
  const int l = tid & 63, w = tid >> 6;
  const int r16 = l & 15, g = l >> 4;
  const int nbase = blockIdx.x * EB;

  {
    const int er = tid >> 2, cb = (tid & 3) * 8;
    int n = nbase + er;
    if (n >= N_NODES) n = N_NODES - 1;
    const unsigned short* ps = hbf + (size_t)n * DIM;
    const float* pm = mi_g + (size_t)n * DIM;
#pragma unroll
    for (int j = 0; j < 8; ++j) {
      const int c = cb + j;
      int4 v;
      if (c < 16) {
        v = *(const int4*)(ps + c * 8);
      } else {
        const float4 f0 = *(const float4*)(pm + (c - 16) * 8);
        const float4 f1 = *(const float4*)(pm + (c - 16) * 8 + 4);
        v.x = (int)f2bf(f0.x) | ((int)f2bf(f0.y) << 16);
        v.y = (int)f2bf(f0.z) | ((int)f2bf(f0.w) << 16);
        v.z = (int)f2bf(f1.x) | ((int)f2bf(f1.y) << 16);
        v.w = (int)f2bf(f1.z) | ((int)f2bf(f1.w) << 16);
      }
      *(int4*)&Abuf[er * 256 + ((c ^ (er & 7)) << 3)] = v;
    }
  }
  __syncthreads();

  f32x4 acc[4][2];
#pragma unroll
  for (int m_ = 0; m_ < 4; ++m_)
#pragma unroll
    for (int ni = 0; ni < 2; ++ni) acc[m_][ni] = (f32x4){0.f, 0.f, 0.f, 0.f};

  for (int kb = 0; kb < 8; ++kb) {
    short8v a[4], b[2];
#pragma unroll
    for (int m_ = 0; m_ < 4; ++m_) {
      const int er = m_ * 16 + r16;
      const int chunk = kb * 4 + g;
      a[m_] = *(const short8v*)&Abuf[er * 256 + ((chunk ^ (er & 7)) << 3)];
    }
#pragma unroll
    for (int ni = 0; ni < 2; ++ni) {
      const int o = w * 32 + ni * 16 + r16;
      b[ni] = *(const short8v*)&fw1[o * 256 + kb * 32 + g * 8];
    }
#pragma unroll
    for (int m_ = 0; m_ < 4; ++m_)
#pragma unroll
      for (int ni = 0; ni < 2; ++ni)
        acc[m_][ni] = __builtin_amdgcn_mfma_f32_16x16x32_bf16(a[m_], b[ni], acc[m_][ni], 0, 0, 0);
  }
  __syncthreads();  // Abuf reads done before A2 overwrite

  {
    const int o0 = w * 32 + r16, o1 = o0 + 16;
    const float bb0 = fb1[o0], bb1 = fb1[o1];
#pragma unroll
    for (int m_ = 0; m_ < 4; ++m_)
#pragma unroll
      for (int r = 0; r < 4; ++r) {
        const int er = m_ * 16 + g * 4 + r;
        A2[er * 128 + (o0 ^ ((er & 7) << 3))] = f2bf(silu_f(acc[m_][0][r] + bb0));
        A2[er * 128 + (o1 ^ ((er & 7) << 3))] = f2bf(silu_f(acc[m_][1][r] + bb1));
      }
  }
  __syncthreads();

  f32x4 acc2[4][2];
#pragma unroll
  for (int m_ = 0; m_ < 4; ++m_)
#pragma unroll
    for (int ni = 0; ni < 2; ++ni) acc2[m_][ni] = (f32x4){0.f, 0.f, 0.f, 0.f};

  for (int kb = 0; kb < 4; ++kb) {
    short8v a[4], b[2];
    const int k0 = kb * 32 + g * 8;
#pragma unroll
    for (int m_ = 0; m_ < 4; ++m_) {
      const int er = m_ * 16 + r16;
      a[m_] = *(const short8v*)&A2[er * 128 + (k0 ^ ((er & 7) << 3))];
    }
#pragma unroll
    for (int ni = 0; ni < 2; ++ni) {
      const int o = w * 32 + ni * 16 + r16;
      b[ni] = *(const short8v*)&fw2[o * 128 + k0];
    }
#pragma unroll
    for (int m_ = 0; m_ < 4; ++m_)
#pragma unroll
      for (int ni = 0; ni < 2; ++ni)
        acc2[m_][ni] = __builtin_amdgcn_mfma_f32_16x16x32_bf16(a[m_], b[ni], acc2[m_][ni], 0, 0, 0);
  }

  // epilogue: out = BN(h) + update   (BN recomputed in fp32 from h and stats)
#pragma unroll
  for (int ni = 0; ni < 2; ++ni) {
    const int o = w * 32 + ni * 16 + r16;
    const float bb = fb2[o];
    const float sc = stats[2 * DIM + o];
    const float sh = stats[3 * DIM + o];
#pragma unroll
    for (int m_ = 0; m_ < 4; ++m_)
#pragma unroll
      for (int r = 0; r < 4; ++r) {
        const int n = nbase + m_ * 16 + g * 4 + r;
        if (n < N_NODES) {
          const float hv = h[(size_t)n * DIM + o];
          out[(size_t)n * DIM + o] = hv * sc + sh + acc2[m_][ni][r] + bb;
        }
      }
  }
}

// ---------------- e passthrough (as float values) ----------------
__global__ void ecopy_kernel(const int* __restrict__ e, float* __restrict__ out_e) {
  const int i4 = blockIdx.x * blockDim.x + threadIdx.x;
  if (i4 >= 2 * N_EDGES / 4) return;
  const int4 v = ((const int4*)e)[i4];
  float4 o;
  o.x = (float)v.x;
  o.y = (float)v.y;
  o.z = (float)v.z;
  o.w = (float)v.w;
  ((float4*)out_e)[i4] = o;
}

extern "C" void kernel_launch(void* const* d_in, const int* in_sizes, int n_in, void* d_out,
                              int out_size, void* d_ws, size_t ws_size, hipStream_t stream) {
  const float* h = (const float*)d_in[0];
  const float* x = (const float*)d_in[1];
  const int* e = (const int*)d_in[2];
  const float* bn_gamma = (const float*)d_in[3];
  const float* bn_beta = (const float*)d_in[4];
  const float* fe_w1 = (const float*)d_in[5];
  const float* fe_b1 = (const float*)d_in[6];
  const float* fe_w2 = (const float*)d_in[7];
  const float* fe_b2 = (const float*)d_in[8];
  const float* finf_w = (const float*)d_in[9];
  const float* finf_b = (const float*)d_in[10];
  const float* fh_w1 = (const float*)d_in[11];
  const float* fh_b1 = (const float*)d_in[12];
  const float* fh_w2 = (const float*)d_in[13];
  const float* fh_b2 = (const float*)d_in[14];

  char* wp = (char*)d_ws;
  auto alloc = [&](size_t bytes) -> char* {
    char* p = wp;
    wp += (bytes + 255) & ~(size_t)255;
    return p;
  };
  float* stats = (float*)alloc(512 * sizeof(float));
  unsigned short* hbf = (unsigned short*)alloc((size_t)N_NODES * DIM * 2);
  unsigned short* w1bf = (unsigned short*)alloc(128 * 256 * 2);
  float* w1col = (float*)alloc(128 * 4);
  unsigned short* w2bf = (unsigned short*)alloc(128 * 128 * 2);
  unsigned short* fw1bf = (unsigned short*)alloc(128 * 256 * 2);
  unsigned short* fw2bf = (unsigned short*)alloc(128 * 128 * 2);
  int* cnt = (int*)alloc((size_t)N_NODES * 4);
  int* cursor = (int*)alloc((size_t)N_NODES * 4);
  int* bsum = (int*)alloc((size_t)SCAN_B * 4);
  int* srcS = (int*)alloc((size_t)N_EDGES * 4);
  int* dstS = (int*)alloc((size_t)N_EDGES * 4);
  float* distS = (float*)alloc((size_t)N_EDGES * 4);
  float* mi_g = (float*)alloc((size_t)N_NODES * DIM * 4);

  float* out = (float*)d_out;
  float* out_e = out + (size_t)N_NODES * DIM;

  hipMemsetAsync(stats, 0, 512 * sizeof(float), stream);
  hipMemsetAsync(cnt, 0, N_NODES * sizeof(int), stream);
  hipMemsetAsync(mi_g, 0, (size_t)N_NODES * DIM * sizeof(float), stream);

  bn_stats_kernel<<<256, 256, 0, stream>>>(h, stats);
  bn_finalize_kernel<<<1, 128, 0, stream>>>(stats, bn_gamma, bn_beta);
  bn_apply_bf_kernel<<<(N_NODES * DIM / 4 + 255) / 256, 256, 0, stream>>>(h, stats, hbf);
  prep_weights_kernel<<<(98432 + 255) / 256, 256, 0, stream>>>(fe_w1, fe_w2, fh_w1, fh_w2, w1bf,
                                                               w1col, w2bf, fw1bf, fw2bf);
  hist_kernel<<<(N_EDGES + 255) / 256, 256, 0, stream>>>(e, cnt);
  scanA_kernel<<<SCAN_B, 256, 0, stream>>>(cnt, bsum);
  scanB_kernel<<<1, 256, 0, stream>>>(bsum);
  scanC_kernel<<<SCAN_B, 256, 0, stream>>>(cnt, bsum, cursor);
  sort_scatter_kernel<<<(N_EDGES + 255) / 256, 256, 0, stream>>>(e, x, cursor, srcS, dstS, distS);

  edge_mfma_kernel<<<N_EDGES / EB, 256, 0, stream>>>(hbf, srcS, dstS, distS, w1bf, w1col, fe_b1,
                                                     w2bf, fe_b2, finf_w, finf_b, mi_g);
  node_mfma_kernel<<<(N_NODES + EB - 1) / EB, 256, 0, stream>>>(hbf, mi_g, h, stats, fw1bf, fh_b1,
                                                                fw2bf, fh_b2, out);
  ecopy_kernel<<<(2 * N_EDGES / 4 + 255) / 256, 256, 0, stream>>>(e, out_e);
}